// Round 1
// baseline (968.841 us; speedup 1.0000x reference)
//
#include <hip/hip_runtime.h>
#include <hip/hip_bf16.h>

typedef __bf16 bf16x8 __attribute__((ext_vector_type(8)));
typedef float floatx4 __attribute__((ext_vector_type(4)));

#define B_  16
#define P_  512
#define L_  12
#define H_  12
#define DH_ 64
#define M_  13
#define D_  768
#define K_  (L_*H_*DH_)   /* 9216 */
#define ROWS (B_*P_)      /* 8192 */

#define BM 128
#define BN 128
#define BK 32
#define LDK 40            /* padded LDS row stride in bf16 elems (80 B) */

// ---------------------------------------------------------------------------
// Kernel 0: cb[b][d] = post_bias[d] + sum_m (1-mlp_mask)*mlp_constants
//                                   + sum_lh (1-attn_mask)*attn_constants
// ---------------------------------------------------------------------------
__global__ void cb_kernel(const float* __restrict__ mlp_mask,
                          const float* __restrict__ attn_mask,
                          const float* __restrict__ mlp_constants,
                          const float* __restrict__ attn_constants,
                          const float* __restrict__ post_bias,
                          float* __restrict__ cb) {
    int d = blockIdx.x * 128 + threadIdx.x;
    int b = blockIdx.y;
    float acc = post_bias[d];
    #pragma unroll
    for (int m = 0; m < M_; ++m)
        acc += (1.0f - mlp_mask[b*M_ + m]) * mlp_constants[m*D_ + d];
    for (int lh = 0; lh < L_*H_; ++lh)
        acc += (1.0f - attn_mask[b*L_*H_ + lh]) * attn_constants[lh*D_ + d];
    cb[b*D_ + d] = acc;
}

// ---------------------------------------------------------------------------
// Kernel 1: fused GEMM  out[r][d] = sum_kk (mask*A)[r][kk] * W[kk][d]
//                                 + sum_m mlp_mask[b][m]*mlp_cache[r][m][d]
//                                 + cb[b][d]
// A = attn_cache viewed as [8192][9216] row-major (contiguous rows).
// W = W_O viewed as [9216][768] row-major.
// 128x128x32 tile, 256 threads = 4 waves in 2x2, each wave 64x64 via
// 4x4 grid of mfma_f32_16x16x32_bf16.
// ---------------------------------------------------------------------------
__global__ __launch_bounds__(256, 2)
void gemm_fused(const float* __restrict__ attn_cache,
                const float* __restrict__ W_O,
                const float* __restrict__ attn_mask,
                const float* __restrict__ mlp_mask,
                const float* __restrict__ mlp_cache,
                const float* __restrict__ cb,
                float* __restrict__ out) {
    __shared__ __bf16 sA[BM * LDK];
    __shared__ __bf16 sB[BN * LDK];   // stored transposed: [n][k]
    __shared__ float sAmask[L_*H_];
    __shared__ float sMlp[M_];

    const int tid   = threadIdx.x;
    const int n0    = blockIdx.x * BN;      // d-tile origin (0..5 * 128)
    const int rbase = blockIdx.y * BM;      // row-tile origin (0..63 * 128)
    const int b     = rbase >> 9;           // 512 rows per batch -> uniform

    if (tid < L_*H_) sAmask[tid] = attn_mask[b*L_*H_ + tid];
    if (tid < M_)    sMlp[tid]   = mlp_mask[b*M_ + tid];

    // A staging: thread -> (row, 16-wide k segment); 4 float4 loads
    const int arow  = tid >> 1;             // 0..127
    const int akseg = (tid & 1) * 16;       // 0 or 16
    const float* aSrcBase = attn_cache + (size_t)(rbase + arow) * K_ + akseg;

    // B staging: thread -> (n col, 16-deep k run); 16 scalar loads (coalesced
    // across lanes along n), written transposed as one row of sB[n][k]
    const int bn  = tid & 127;              // 0..127
    const int bkh = (tid >> 7) * 16;        // 0 or 16
    const float* bSrcBase = W_O + (size_t)bkh * D_ + n0 + bn;

    const int wave = tid >> 6;
    const int lane = tid & 63;
    const int wm   = (wave >> 1) * 64;
    const int wn   = (wave & 1) * 64;
    const int quad = lane >> 4;
    const int ln   = lane & 15;

    floatx4 acc[4][4];
    #pragma unroll
    for (int i = 0; i < 4; ++i)
        #pragma unroll
        for (int j = 0; j < 4; ++j)
            acc[i][j] = (floatx4){0.f, 0.f, 0.f, 0.f};

    for (int k0 = 0; k0 < K_; k0 += BK) {
        __syncthreads();   // previous iter's fragment reads done (also guards sAmask/sMlp init)
        // ---- stage A tile (mask folded in, fp32 -> bf16) ----
        {
            const float4* src = (const float4*)(aSrcBase + k0);
            __bf16 buf[16];
            #pragma unroll
            for (int i = 0; i < 4; ++i) {
                float4 v = src[i];
                float msk = sAmask[(k0 + akseg + i*4) >> 6];  // kk>>6 = l*12+h
                buf[i*4+0] = (__bf16)(v.x * msk);
                buf[i*4+1] = (__bf16)(v.y * msk);
                buf[i*4+2] = (__bf16)(v.z * msk);
                buf[i*4+3] = (__bf16)(v.w * msk);
            }
            *(bf16x8*)&sA[arow*LDK + akseg]     = *(bf16x8*)&buf[0];
            *(bf16x8*)&sA[arow*LDK + akseg + 8] = *(bf16x8*)&buf[8];
        }
        // ---- stage B tile transposed: sB[n][k] ----
        {
            const float* src = bSrcBase + (size_t)k0 * D_;
            __bf16 buf[16];
            #pragma unroll
            for (int j = 0; j < 16; ++j)
                buf[j] = (__bf16)src[(size_t)j * D_];
            *(bf16x8*)&sB[bn*LDK + bkh]     = *(bf16x8*)&buf[0];
            *(bf16x8*)&sB[bn*LDK + bkh + 8] = *(bf16x8*)&buf[8];
        }
        __syncthreads();

        // ---- fragments + MFMA ----
        bf16x8 af[4], bfr[4];
        #pragma unroll
        for (int i = 0; i < 4; ++i)
            af[i] = *(const bf16x8*)&sA[(wm + i*16 + ln)*LDK + quad*8];
        #pragma unroll
        for (int j = 0; j < 4; ++j)
            bfr[j] = *(const bf16x8*)&sB[(wn + j*16 + ln)*LDK + quad*8];
        #pragma unroll
        for (int i = 0; i < 4; ++i)
            #pragma unroll
            for (int j = 0; j < 4; ++j)
                acc[i][j] = __builtin_amdgcn_mfma_f32_16x16x32_bf16(
                                af[i], bfr[j], acc[i][j], 0, 0, 0);
    }

    // ---- epilogue: + mlp stream + cb, store fp32 ----
    // C/D layout (verified m89/m91): col = lane&15, row = quad*4 + reg
    #pragma unroll
    for (int i = 0; i < 4; ++i) {
        #pragma unroll
        for (int j = 0; j < 4; ++j) {
            const int d   = n0 + wn + j*16 + ln;
            const float cbv = cb[b*D_ + d];
            const int rloc = wm + i*16 + quad*4;
            #pragma unroll
            for (int v = 0; v < 4; ++v) {
                const int r = rbase + rloc + v;
                float s = acc[i][j][v] + cbv;
                const float* mc = mlp_cache + (size_t)r * (M_*D_) + d;
                #pragma unroll
                for (int m = 0; m < M_; ++m)
                    s += sMlp[m] * mc[(size_t)m * D_];
                out[(size_t)r * D_ + d] = s;
            }
        }
    }
}

// ---------------------------------------------------------------------------
extern "C" void kernel_launch(void* const* d_in, const int* in_sizes, int n_in,
                              void* d_out, int out_size, void* d_ws, size_t ws_size,
                              hipStream_t stream) {
    const float* mlp_cache      = (const float*)d_in[0];
    const float* attn_cache     = (const float*)d_in[1];
    const float* mlp_mask       = (const float*)d_in[2];
    const float* attn_mask      = (const float*)d_in[3];
    const float* mlp_constants  = (const float*)d_in[4];
    const float* attn_constants = (const float*)d_in[5];
    const float* W_O            = (const float*)d_in[6];
    const float* post_bias      = (const float*)d_in[7];
    float* out = (float*)d_out;
    float* cb  = (float*)d_ws;   // 16*768*4 = 49152 B of scratch

    cb_kernel<<<dim3(D_/128, B_), 128, 0, stream>>>(
        mlp_mask, attn_mask, mlp_constants, attn_constants, post_bias, cb);

    gemm_fused<<<dim3(D_/BN, ROWS/BM), 256, 0, stream>>>(
        attn_cache, W_O, attn_mask, mlp_mask, mlp_cache, cb, out);
}